// Round 5
// baseline (697.593 us; speedup 1.0000x reference)
//
#include <hip/hip_runtime.h>
#include <cstddef>
#include <cstdint>

#define C 256

typedef __attribute__((ext_vector_type(8))) short short8;
typedef __attribute__((ext_vector_type(4))) float f32x4;

__device__ __forceinline__ ushort f2bf(float f) {
    uint32_t u = __float_as_uint(f);
    u += 0x7FFF + ((u >> 16) & 1);   // round-to-nearest-even
    return (ushort)(u >> 16);
}
__device__ __forceinline__ float bf2f(ushort u) {
    return __uint_as_float(((uint32_t)u) << 16);
}
__device__ __forceinline__ uint2 pack4(float a, float b, float c, float d) {
    uint2 o;
    o.x = (uint32_t)f2bf(a) | ((uint32_t)f2bf(b) << 16);
    o.y = (uint32_t)f2bf(c) | ((uint32_t)f2bf(d) << 16);
    return o;
}
__device__ __forceinline__ void acc8(uint4 v, float* a) {
    a[0] += bf2f((ushort)(v.x & 0xffff)); a[1] += bf2f((ushort)(v.x >> 16));
    a[2] += bf2f((ushort)(v.y & 0xffff)); a[3] += bf2f((ushort)(v.y >> 16));
    a[4] += bf2f((ushort)(v.z & 0xffff)); a[5] += bf2f((ushort)(v.z >> 16));
    a[6] += bf2f((ushort)(v.w & 0xffff)); a[7] += bf2f((ushort)(v.w >> 16));
}

// ---------------- cast: x + Wl0 + Wr0 -> bf16, perfectly coalesced ----------------
// lane i: load float4 src[i] (16B, consecutive across wave), store uint2 dst[i] (8B, consecutive).
__global__ __launch_bounds__(256) void cast_kernel(
        const float4* __restrict__ x4, int nx4, uint2* __restrict__ xbf,
        const float4* __restrict__ wl0f, const float4* __restrict__ wr0f,
        uint2* __restrict__ wl0b, uint2* __restrict__ wr0b) {
    const int nw4 = C * C / 4;                 // 16384 per matrix
    const int total = nx4 + 2 * nw4;
    const int stride = gridDim.x * blockDim.x;
    for (int i = blockIdx.x * blockDim.x + threadIdx.x; i < total; i += stride) {
        if (i < nx4) {
            float4 v = x4[i];
            xbf[i] = pack4(v.x, v.y, v.z, v.w);
        } else if (i < nx4 + nw4) {
            int j = i - nx4;
            float4 v = wl0f[j];
            wl0b[j] = pack4(v.x, v.y, v.z, v.w);
        } else {
            int j = i - nx4 - nw4;
            float4 v = wr0f[j];
            wr0b[j] = pack4(v.x, v.y, v.z, v.w);
        }
    }
}

// ---------------- histograms (both layers), isolated for timing ----------------
#define HB0 2048
#define HB1 1024
__global__ __launch_bounds__(256) void hist_kernel(
        const int* __restrict__ e0d, int* __restrict__ cnt0, int E0,
        const int* __restrict__ e1d, int* __restrict__ cnt1, int E1) {
    const int b = blockIdx.x;
    if (b < HB0) {
        const int stride = HB0 * 256;
        for (int i = b * 256 + threadIdx.x; i < E0; i += stride)
            atomicAdd(&cnt0[e0d[i]], 1);
    } else {
        const int stride = HB1 * 256;
        for (int i = (b - HB0) * 256 + threadIdx.x; i < E1; i += stride)
            atomicAdd(&cnt1[e1d[i]], 1);
    }
}

// ---------------- dual exclusive scan, writes off[n] sentinel ----------------
__global__ __launch_bounds__(1024) void scan2_kernel(
        const int* __restrict__ cnt0, int* __restrict__ off0, int n0,
        const int* __restrict__ cnt1, int* __restrict__ off1, int n1) {
    const int* cnt = blockIdx.x ? cnt1 : cnt0;
    int* off = blockIdx.x ? off1 : off0;
    int n = blockIdx.x ? n1 : n0;
    __shared__ int buf[1024];
    int chunk = (n + 1023) >> 10;
    int lo = (int)threadIdx.x * chunk;
    int hi = min(lo + chunk, n);
    int s = 0;
    for (int i = lo; i < hi; ++i) s += cnt[i];
    buf[threadIdx.x] = s;
    __syncthreads();
    int xv = s;
    for (int d = 1; d < 1024; d <<= 1) {
        int t = ((int)threadIdx.x >= d) ? buf[threadIdx.x - d] : 0;
        __syncthreads();
        xv += t;
        buf[threadIdx.x] = xv;
        __syncthreads();
    }
    int run = xv - s;
    for (int i = lo; i < hi; ++i) { off[i] = run; run += cnt[i]; }
    if (lo < n && hi == n) off[n] = run;   // sentinel (total)
}

// ---------------- fused scatter; cnt used as decrementing cursor ----------------
__global__ void scatter2_kernel(
        const int* __restrict__ s0, const int* __restrict__ d0,
        const int* __restrict__ off0, int* __restrict__ cnt0, int* __restrict__ esrc0, int E0,
        const int* __restrict__ s1, const int* __restrict__ d1,
        const int* __restrict__ off1, int* __restrict__ cnt1, int* __restrict__ esrc1, int E1) {
    int e = blockIdx.x * blockDim.x + threadIdx.x;
    if (e < E0) {
        int d = d0[e];
        int old = atomicSub(&cnt0[d], 1);
        esrc0[off0[d] + old - 1] = s0[e];
    } else if (e < E0 + E1) {
        int i = e - E0;
        int d = d1[i];
        int old = atomicSub(&cnt1[d], 1);
        esrc1[off1[d] + old - 1] = s1[i];
    }
}

// ---------------- mean aggregation: one wave/target, 4 rows in flight per half ----------------
__global__ __launch_bounds__(256) void aggregate_kernel(const uint4* __restrict__ xb4,
        const int* __restrict__ esrc, const int* __restrict__ off,
        uint4* __restrict__ out4, int n_tgt) {
    const int lane = threadIdx.x & 63;
    const int half = lane >> 5, l31 = lane & 31;
    const int t = blockIdx.x * 4 + (threadIdx.x >> 6);
    if (t >= n_tgt) return;
    const int base = off[t];
    const int deg = off[t + 1] - base;
    float a[8] = {0.f, 0.f, 0.f, 0.f, 0.f, 0.f, 0.f, 0.f};
    int i = 0;
    for (; i + 8 <= deg; i += 8) {
        int s0 = esrc[base + i + half];
        int s1 = esrc[base + i + 2 + half];
        int s2 = esrc[base + i + 4 + half];
        int s3 = esrc[base + i + 6 + half];
        uint4 v0 = xb4[(size_t)s0 * 32 + l31];
        uint4 v1 = xb4[(size_t)s1 * 32 + l31];
        uint4 v2 = xb4[(size_t)s2 * 32 + l31];
        uint4 v3 = xb4[(size_t)s3 * 32 + l31];
        acc8(v0, a); acc8(v1, a); acc8(v2, a); acc8(v3, a);
    }
    for (; i + 2 <= deg; i += 2) {
        int s = esrc[base + i + half];
        uint4 v = xb4[(size_t)s * 32 + l31];
        acc8(v, a);
    }
    if ((deg & 1) && half == 0) {
        int s = esrc[base + deg - 1];
        uint4 v = xb4[(size_t)s * 32 + l31];
        acc8(v, a);
    }
#pragma unroll
    for (int j = 0; j < 8; ++j) a[j] += __shfl_xor(a[j], 32, 64);
    if (half == 0) {
        float inv = 1.0f / (float)(deg > 1 ? deg : 1);
        uint4 o;
        o.x = (uint32_t)f2bf(a[0] * inv) | ((uint32_t)f2bf(a[1] * inv) << 16);
        o.y = (uint32_t)f2bf(a[2] * inv) | ((uint32_t)f2bf(a[3] * inv) << 16);
        o.z = (uint32_t)f2bf(a[4] * inv) | ((uint32_t)f2bf(a[5] * inv) << 16);
        o.w = (uint32_t)f2bf(a[6] * inv) | ((uint32_t)f2bf(a[7] * inv) << 16);
        out4[(size_t)t * 32 + l31] = o;
    }
}

// ---------------- fallback: fp32 gather -> bf16 aggr ----------------
__global__ __launch_bounds__(256) void aggregate_f32_kernel(const float4* __restrict__ x4,
        const int* __restrict__ esrc, const int* __restrict__ off,
        uint2* __restrict__ aggr, int n_tgt) {
    int w = threadIdx.x >> 6;
    int lane = threadIdx.x & 63;
    int t = blockIdx.x * 4 + w;
    if (t >= n_tgt) return;
    int base = off[t];
    int deg = off[t + 1] - base;
    float4 acc = make_float4(0.f, 0.f, 0.f, 0.f);
    for (int i = 0; i < deg; ++i) {
        int s = esrc[base + i];
        float4 v = x4[(size_t)s * 64 + lane];
        acc.x += v.x; acc.y += v.y; acc.z += v.z; acc.w += v.w;
    }
    float inv = 1.0f / (float)(deg > 1 ? deg : 1);
    aggr[(size_t)t * 64 + lane] = pack4(acc.x * inv, acc.y * inv, acc.z * inv, acc.w * inv);
}

// ---------------- MFMA GEMM: h = relu([A|Axt] @ [Wl;Wr]^T + b), bf16 out + col stats ----------------
#define TM 128
#define TN 128
#define LDK 40

__global__ __launch_bounds__(256) void gemm_bn_mfma(
        const ushort* __restrict__ Aagg, const ushort* __restrict__ Axt,
        const ushort* __restrict__ Wl,  const ushort* __restrict__ Wr,
        const float* __restrict__ bias,
        ushort* __restrict__ h, float* __restrict__ colsum, float* __restrict__ colsq,
        int M) {
    __shared__ ushort As[TM * LDK];
    __shared__ ushort Bs[TN * LDK];
    __shared__ float csum[TN];
    __shared__ float csq[TN];

    const int tid = threadIdx.x;
    const int m0 = blockIdx.y * TM;
    const int n0 = blockIdx.x * TN;
    const int wid = tid >> 6, lane = tid & 63;
    const int l15 = lane & 15, quad = lane >> 4;
    const int wm = (wid & 1) * 64, wn = (wid >> 1) * 64;

    if (tid < TN) { csum[tid] = 0.f; csq[tid] = 0.f; }

    const int srow = tid >> 2;
    const int skoff = (tid & 3) * 8;

    f32x4 acc[4][4];
#pragma unroll
    for (int i = 0; i < 4; ++i)
#pragma unroll
        for (int j = 0; j < 4; ++j) acc[i][j] = (f32x4){0.f, 0.f, 0.f, 0.f};

#pragma unroll 1
    for (int kt = 0; kt < 16; ++kt) {
        const int ks = kt * 32;
        const ushort* Ab = (ks < 256) ? Aagg : Axt;
        const ushort* Bb = (ks < 256) ? Wl : Wr;
        const int k0 = ks & 255;
        int r0 = min(m0 + srow, M - 1);
        int r1 = min(m0 + srow + 64, M - 1);
        uint4 a0 = *(const uint4*)&Ab[(size_t)r0 * C + k0 + skoff];
        uint4 a1 = *(const uint4*)&Ab[(size_t)r1 * C + k0 + skoff];
        uint4 b0 = *(const uint4*)&Bb[(size_t)(n0 + srow) * C + k0 + skoff];
        uint4 b1 = *(const uint4*)&Bb[(size_t)(n0 + srow + 64) * C + k0 + skoff];
        __syncthreads();
        *(uint4*)&As[srow * LDK + skoff] = a0;
        *(uint4*)&As[(srow + 64) * LDK + skoff] = a1;
        *(uint4*)&Bs[srow * LDK + skoff] = b0;
        *(uint4*)&Bs[(srow + 64) * LDK + skoff] = b1;
        __syncthreads();

        short8 af[4], bw[4];
#pragma unroll
        for (int mi = 0; mi < 4; ++mi)
            af[mi] = *(const short8*)&As[(wm + mi * 16 + l15) * LDK + quad * 8];
#pragma unroll
        for (int ni = 0; ni < 4; ++ni)
            bw[ni] = *(const short8*)&Bs[(wn + ni * 16 + l15) * LDK + quad * 8];
#pragma unroll
        for (int mi = 0; mi < 4; ++mi)
#pragma unroll
            for (int ni = 0; ni < 4; ++ni)
                acc[mi][ni] = __builtin_amdgcn_mfma_f32_16x16x32_bf16(
                    af[mi], bw[ni], acc[mi][ni], 0, 0, 0);
    }

    float lsum[4] = {0.f, 0.f, 0.f, 0.f};
    float lsq[4]  = {0.f, 0.f, 0.f, 0.f};
#pragma unroll
    for (int ni = 0; ni < 4; ++ni) {
        const int col = wn + ni * 16 + l15;
        const float bv = bias[n0 + col];
#pragma unroll
        for (int mi = 0; mi < 4; ++mi) {
#pragma unroll
            for (int r = 0; r < 4; ++r) {
                int m = m0 + wm + mi * 16 + quad * 4 + r;
                float v = acc[mi][ni][r] + bv;
                v = fmaxf(v, 0.f);
                if (m < M) {
                    h[(size_t)m * C + n0 + col] = f2bf(v);
                    lsum[ni] += v;
                    lsq[ni] += v * v;
                }
            }
        }
    }
#pragma unroll
    for (int ni = 0; ni < 4; ++ni) {
        const int col = wn + ni * 16 + l15;
        atomicAdd(&csum[col], lsum[ni]);
        atomicAdd(&csq[col], lsq[ni]);
    }
    __syncthreads();
    if (tid < TN) {
        atomicAdd(&colsum[n0 + tid], csum[tid]);
        atomicAdd(&colsq[n0 + tid], csq[tid]);
    }
}

// ---------------- fixup: fold norm0 into layer-1 weights/bias ----------------
__global__ __launch_bounds__(256) void fixup_kernel(
        const float* __restrict__ colsum, const float* __restrict__ colsq, float invN,
        const float* __restrict__ g0, const float* __restrict__ be0,
        const float* __restrict__ Wl1, const float* __restrict__ Wr1,
        const float* __restrict__ bl1,
        ushort* __restrict__ wl1b, ushort* __restrict__ wr1b, float* __restrict__ bias1) {
    __shared__ float ss[C], st[C];
    __shared__ float red[256];
    const int k = threadIdx.x;
    {
        float m = colsum[k] * invN;
        float v = colsq[k] * invN - m * m;
        float r = rsqrtf(fmaxf(v, 0.f) + 1e-5f);
        float s = g0[k] * r;
        ss[k] = s;
        st[k] = be0[k] - m * s;
    }
    __syncthreads();
    const int n = blockIdx.x;
    float wl = Wl1[(size_t)n * C + k];
    float wr = Wr1[(size_t)n * C + k];
    wl1b[(size_t)n * C + k] = f2bf(wl * ss[k]);
    wr1b[(size_t)n * C + k] = f2bf(wr * ss[k]);
    red[k] = st[k] * (wl + wr);
    __syncthreads();
    for (int d = 128; d > 0; d >>= 1) {
        if (k < d) red[k] += red[k + d];
        __syncthreads();
    }
    if (k == 0) bias1[n] = bl1[n] + red[0];
}

// ---------------- norm1 (+ fused stat finalize): bf16 in -> fp32 out ----------------
__global__ __launch_bounds__(256) void norm1_kernel(const uint2* __restrict__ hin,
        const float* __restrict__ colsum, const float* __restrict__ colsq, float invN,
        const float* __restrict__ gamma, const float* __restrict__ beta,
        float4* __restrict__ outp, int n4) {
    __shared__ float smu[C], srs[C];
    {
        int k = threadIdx.x;
        float m = colsum[k] * invN;
        float v = colsq[k] * invN - m * m;
        smu[k] = m;
        srs[k] = rsqrtf(fmaxf(v, 0.f) + 1e-5f);
    }
    __syncthreads();
    int i = blockIdx.x * blockDim.x + threadIdx.x;
    if (i >= n4) return;
    int c = (i & 63) << 2;
    uint2 v = hin[i];
    float4 o;
    o.x = gamma[c + 0] * (bf2f((ushort)(v.x & 0xffff)) - smu[c + 0]) * srs[c + 0] + beta[c + 0];
    o.y = gamma[c + 1] * (bf2f((ushort)(v.x >> 16))    - smu[c + 1]) * srs[c + 1] + beta[c + 1];
    o.z = gamma[c + 2] * (bf2f((ushort)(v.y & 0xffff)) - smu[c + 2]) * srs[c + 2] + beta[c + 2];
    o.w = gamma[c + 3] * (bf2f((ushort)(v.y >> 16))    - smu[c + 3]) * srs[c + 3] + beta[c + 3];
    outp[i] = o;
}

extern "C" void kernel_launch(void* const* d_in, const int* in_sizes, int n_in,
                              void* d_out, int out_size, void* d_ws, size_t ws_size,
                              hipStream_t stream) {
    const float* x   = (const float*)d_in[0];
    const int* e0s   = (const int*)d_in[1];
    const int* e0d   = (const int*)d_in[2];
    const int* e1s   = (const int*)d_in[3];
    const int* e1d   = (const int*)d_in[4];
    const float* Wl0 = (const float*)d_in[5];
    const float* bl0 = (const float*)d_in[6];
    const float* Wr0 = (const float*)d_in[7];
    const float* ga0 = (const float*)d_in[8];
    const float* be0 = (const float*)d_in[9];
    const float* Wl1 = (const float*)d_in[10];
    const float* bl1 = (const float*)d_in[11];
    const float* Wr1 = (const float*)d_in[12];
    const float* ga1 = (const float*)d_in[13];
    const float* be1 = (const float*)d_in[14];

    const int N0 = 200000, N1 = 50000, N2 = 12500;
    const int E0 = in_sizes[1];
    const int E1 = in_sizes[3];

    char* ws = (char*)d_ws;
    size_t o = 0;
    auto alloc = [&](size_t bytes) -> char* {
        char* p = ws + o;
        o += (bytes + 255) & ~(size_t)255;
        return p;
    };

    const size_t common =
        (size_t)N1 * C * 2 * 2 + (size_t)E0 * 4 + (size_t)E1 * 4 +
        ((size_t)N1 + N2 + 8 * C) * 4 + ((size_t)N1 + N2 + 2) * 4 +
        4 * (size_t)C * C * 2 + C * 4 + 65536;
    const bool full = ws_size >= common + (size_t)N0 * C * 2;

    // zeroed region: cnt0 | cnt1 | stats (single memset)
    int* cnt0 = (int*)alloc(((size_t)N1 + N2 + 8 * C) * sizeof(int));
    int* cnt1 = cnt0 + N1;
    float* stats = (float*)(cnt1 + N2);
    float* colsum0 = stats,         *colsq0 = stats + C;
    float* colsum1 = stats + 4 * C, *colsq1 = stats + 5 * C;
    const size_t zbytes = ((size_t)N1 + N2 + 8 * C) * sizeof(int);

    int* off0 = (int*)alloc(((size_t)N1 + 1) * sizeof(int));
    int* off1 = (int*)alloc(((size_t)N2 + 1) * sizeof(int));
    ushort* x_bf  = (ushort*)alloc((full ? (size_t)N0 : (size_t)N1) * C * 2);
    ushort* aggr0 = (ushort*)alloc((size_t)N1 * C * 2);
    ushort* h0raw = (ushort*)alloc((size_t)N1 * C * 2);
    ushort* aggr1 = aggr0;                       // aggr0 dead after gemm0
    ushort* h1raw = aggr0 + (size_t)N2 * C;
    int* esrc0 = (int*)alloc((size_t)E0 * sizeof(int));
    int* esrc1 = (int*)alloc((size_t)E1 * sizeof(int));
    ushort* wbf = (ushort*)alloc(4 * (size_t)C * C * 2);
    ushort* wl0b = wbf, *wr0b = wbf + C * C, *wl1b = wbf + 2 * C * C, *wr1b = wbf + 3 * C * C;
    float* bias1 = (float*)alloc(C * sizeof(float));

    hipMemsetAsync(cnt0, 0, zbytes, stream);

    // cast (pure stream, fully coalesced)
    {
        int nx4 = (full ? N0 : N1) * C / 4;
        cast_kernel<<<6400, 256, 0, stream>>>((const float4*)x, nx4, (uint2*)x_bf,
                                              (const float4*)Wl0, (const float4*)Wr0,
                                              (uint2*)wl0b, (uint2*)wr0b);
    }
    // histograms (isolated)
    hist_kernel<<<HB0 + HB1, 256, 0, stream>>>(e0d, cnt0, E0, e1d, cnt1, E1);
    scan2_kernel<<<2, 1024, 0, stream>>>(cnt0, off0, N1, cnt1, off1, N2);
    scatter2_kernel<<<(E0 + E1 + 255) / 256, 256, 0, stream>>>(
        e0s, e0d, off0, cnt0, esrc0, E0, e1s, e1d, off1, cnt1, esrc1, E1);

    // ---------------- layer 0 ----------------
    if (full)
        aggregate_kernel<<<N1 / 4, 256, 0, stream>>>((const uint4*)x_bf, esrc0, off0,
                                                     (uint4*)aggr0, N1);
    else
        aggregate_f32_kernel<<<N1 / 4, 256, 0, stream>>>((const float4*)x, esrc0, off0,
                                                         (uint2*)aggr0, N1);
    dim3 grid0(C / TN, (N1 + TM - 1) / TM);
    gemm_bn_mfma<<<grid0, 256, 0, stream>>>(aggr0, x_bf, wl0b, wr0b, bl0,
                                            h0raw, colsum0, colsq0, N1);
    fixup_kernel<<<C, 256, 0, stream>>>(colsum0, colsq0, 1.0f / (float)N1,
                                        ga0, be0, Wl1, Wr1, bl1, wl1b, wr1b, bias1);

    // ---------------- layer 1 (operates on RAW h0) ----------------
    aggregate_kernel<<<N2 / 4, 256, 0, stream>>>((const uint4*)h0raw, esrc1, off1,
                                                 (uint4*)aggr1, N2);
    dim3 grid1(C / TN, (N2 + TM - 1) / TM);
    gemm_bn_mfma<<<grid1, 256, 0, stream>>>(aggr1, h0raw, wl1b, wr1b, bias1,
                                            h1raw, colsum1, colsq1, N2);
    int n4_1 = N2 * C / 4;
    norm1_kernel<<<(n4_1 + 255) / 256, 256, 0, stream>>>((const uint2*)h1raw,
                                                         colsum1, colsq1, 1.0f / (float)N2,
                                                         ga1, be1, (float4*)d_out, n4_1);
}